// Round 2
// baseline (2862.468 us; speedup 1.0000x reference)
//
#include <hip/hip_runtime.h>
#include <cstdint>
#include <cstddef>

#define NN 20000      // nodes
#define NE 640000     // edges
#define DD 128        // feature dim
#define NP 10000      // products (output cols)
#define KO 256        // 2*DD

typedef __attribute__((ext_vector_type(8))) short short8;
typedef __attribute__((ext_vector_type(4))) float f32x4;

static __device__ __forceinline__ unsigned short f2bf(float f){
  uint32_t u = __float_as_uint(f);
  return (unsigned short)((u + 0x7fffu + ((u >> 16) & 1u)) >> 16);
}

static __device__ __forceinline__ void gload_lds16(const void* g, void* l){
  __builtin_amdgcn_global_load_lds(
      (const __attribute__((address_space(1))) void*)g,
      (__attribute__((address_space(3))) void*)l, 16, 0, 0);
}

// ---------------- CSR build ----------------
__global__ void k_count(const int* __restrict__ dst, int* __restrict__ cnt, int n){
  int i = blockIdx.x * blockDim.x + threadIdx.x;
  if (i < n) atomicAdd(&cnt[dst[i]], 1);
}

__global__ void k_dinv(const int* __restrict__ cnt, float* __restrict__ dinv, int n){
  int i = blockIdx.x * blockDim.x + threadIdx.x;
  if (i < n) dinv[i] = rsqrtf((float)(cnt[i] + 1));  // +1 self-loop
}

__global__ void k_scan(const int* __restrict__ cnt, int* __restrict__ row_off,
                       int* __restrict__ cursor, int n){
  __shared__ int part[1024];
  int t = threadIdx.x;
  int per = (n + 1023) >> 10;
  int base = t * per;
  int s = 0;
  for (int i = 0; i < per; i++){ int idx = base + i; if (idx < n) s += cnt[idx]; }
  part[t] = s;
  __syncthreads();
  for (int off = 1; off < 1024; off <<= 1){
    int v = (t >= off) ? part[t - off] : 0;
    __syncthreads();
    part[t] += v;
    __syncthreads();
  }
  int run = (t == 0) ? 0 : part[t - 1];
  for (int i = 0; i < per; i++){
    int idx = base + i;
    if (idx < n){ row_off[idx] = run; cursor[idx] = run; run += cnt[idx]; }
  }
  if (t == 0) row_off[n] = part[1023];
}

__global__ void k_fill(const int* __restrict__ src, const int* __restrict__ dst,
                       int* __restrict__ cursor, int* __restrict__ col, int n){
  int i = blockIdx.x * blockDim.x + threadIdx.x;
  if (i < n){
    int p = atomicAdd(&cursor[dst[i]], 1);
    col[p] = src[i];
  }
}

// ---------------- packers (MFMA fragment order) ----------------
// frag layout: chunk[(rowtile*KT + ktile)*64 + k8*16 + fr][e]
//   holds X[rowtile*16 + fr][ktile*32 + k8*8 + e], chunk = 8 bf16 = 16B

// gather embeddings -> fragment order (KT=4, K=128)
__global__ void k_gather_frag(const float* __restrict__ tab, const int* __restrict__ ids,
                              unsigned short* __restrict__ xf){
  int node = blockIdx.x * blockDim.y + threadIdx.y;
  int tx = threadIdx.x;            // covers d = tx*4 .. tx*4+3
  if (node >= NN) return;
  const float4 v = *reinterpret_cast<const float4*>(tab + (size_t)ids[node] * DD + tx * 4);
  ushort4 o; o.x = f2bf(v.x); o.y = f2bf(v.y); o.z = f2bf(v.z); o.w = f2bf(v.w);
  size_t chunk = ((size_t)(node >> 4) * 4 + (tx >> 3)) * 64 + ((tx >> 1) & 3) * 16 + (node & 15);
  *reinterpret_cast<ushort4*>(xf + chunk * 8 + (tx & 1) * 4) = o;
}

// W [K][N] row-major f32 -> B-fragment order bf16 (col plays "row" role)
__global__ void k_wfrag(const float* __restrict__ W, unsigned short* __restrict__ Wf,
                        int N, int lg2kt, int total){
  int i = blockIdx.x * blockDim.x + threadIdx.x;
  if (i >= total) return;
  int e = i & 7, l = (i >> 3) & 63, rem = i >> 9;
  int kt = rem & ((1 << lg2kt) - 1), ct = rem >> lg2kt;
  int col = ct * 16 + (l & 15);
  int k = kt * 32 + (l >> 4) * 8 + e;
  Wf[i] = f2bf(W[(size_t)k * N + col]);
}

// ---------------- conv GEMM: hs = dinv * (x @ W), A in regs, no LDS ----------------
__global__ __launch_bounds__(256) void k_conv(const unsigned short* __restrict__ Af,
        const unsigned short* __restrict__ Wf, const float* __restrict__ dinv,
        float* __restrict__ hs){
  int gw = blockIdx.x * 4 + (threadIdx.x >> 6);
  int lane = threadIdx.x & 63;
  bool valid = gw < (NN / 16);
  int R = valid ? gw : (NN / 16 - 1);
  short8 a[4];
  #pragma unroll
  for (int kt = 0; kt < 4; kt++)
    a[kt] = *reinterpret_cast<const short8*>(Af + ((size_t)(R * 4 + kt) * 64 + lane) * 8);
  int fr = lane & 15, fq = lane >> 4;
  #pragma unroll
  for (int ct = 0; ct < 8; ct++){
    f32x4 acc = {0.f, 0.f, 0.f, 0.f};
    #pragma unroll
    for (int kt = 0; kt < 4; kt++){
      short8 b = *reinterpret_cast<const short8*>(Wf + ((size_t)(ct * 4 + kt) * 64 + lane) * 8);
      acc = __builtin_amdgcn_mfma_f32_16x16x32_bf16(a[kt], b, acc, 0, 0, 0);
    }
    if (valid){
      #pragma unroll
      for (int r = 0; r < 4; r++){
        int grow = R * 16 + fq * 4 + r;
        hs[(size_t)grow * DD + ct * 16 + fr] = dinv[grow] * acc[r];
      }
    }
  }
}

// ---------------- aggregation: out = dinv[n]*(hs[n] + sum_src hs[src]) + b -> frag bf16 ----------------
__global__ void k_agg_frag(const float* __restrict__ hs, const float* __restrict__ dinv,
                           const int* __restrict__ row_off, const int* __restrict__ col,
                           const float* __restrict__ bias, unsigned short* __restrict__ xf,
                           int KT, int toff){
  int node = blockIdx.x * blockDim.y + threadIdx.y;
  int tx = threadIdx.x;
  if (node >= NN) return;
  const float4* h4 = reinterpret_cast<const float4*>(hs);
  float4 acc = h4[(size_t)node * 32 + tx];   // self term (hs pre-scaled by dinv)
  int s = row_off[node], e = row_off[node + 1];
  int i = s;
  for (; i + 1 < e; i += 2){
    int c0 = col[i], c1 = col[i + 1];
    float4 v0 = h4[(size_t)c0 * 32 + tx];
    float4 v1 = h4[(size_t)c1 * 32 + tx];
    acc.x += v0.x + v1.x; acc.y += v0.y + v1.y;
    acc.z += v0.z + v1.z; acc.w += v0.w + v1.w;
  }
  if (i < e){
    float4 v = h4[(size_t)col[i] * 32 + tx];
    acc.x += v.x; acc.y += v.y; acc.z += v.z; acc.w += v.w;
  }
  float dn = dinv[node];
  const float4 b4 = *reinterpret_cast<const float4*>(bias + tx * 4);
  ushort4 o;
  o.x = f2bf(dn * acc.x + b4.x); o.y = f2bf(dn * acc.y + b4.y);
  o.z = f2bf(dn * acc.z + b4.z); o.w = f2bf(dn * acc.w + b4.w);
  size_t chunk = ((size_t)(node >> 4) * KT + toff + (tx >> 3)) * 64 + ((tx >> 1) & 3) * 16 + (node & 15);
  *reinterpret_cast<ushort4*>(xf + chunk * 8 + (tx & 1) * 4) = o;
}

// ---------------- fused output GEMM + softmax ----------------
// grid 250 blocks (1/CU), 4 waves; wave gw owns rowtile gw and (gw<250) rowtile 1000+gw.
// A (K=256) in registers; B staged 80-col steps (40KB) dbuf via global_load_lds;
// pass 0: rowsum of exp in regs; pass 1: recompute, scale, store.
#define CT_STEP 5
#define NSTEPS 125
#define CHUNKS_STEP (CT_STEP * 8 * 64)   // 2560 chunks * 16B = 40KB

__global__ __launch_bounds__(256, 1) void k_out(const unsigned short* __restrict__ Af,
        const unsigned short* __restrict__ Bf, const float* __restrict__ ob,
        float* __restrict__ out){
  __shared__ unsigned short sB[2][CHUNKS_STEP * 8];
  const int tid = threadIdx.x, lane = tid & 63;
  const int gw = blockIdx.x * 4 + (tid >> 6);
  const int fr = lane & 15, fq = lane >> 4;
  const int R0 = gw;                       // < 1000
  const bool has2 = gw < 250;
  const int R1 = has2 ? (1000 + gw) : gw;

  short8 a0[8], a1[8];
  #pragma unroll
  for (int kt = 0; kt < 8; kt++){
    a0[kt] = *reinterpret_cast<const short8*>(Af + ((size_t)(R0 * 8 + kt) * 64 + lane) * 8);
    a1[kt] = *reinterpret_cast<const short8*>(Af + ((size_t)(R1 * 8 + kt) * 64 + lane) * 8);
  }
  float rs0[4] = {0.f, 0.f, 0.f, 0.f}, rs1[4] = {0.f, 0.f, 0.f, 0.f};
  float rinv0[4] = {0.f, 0.f, 0.f, 0.f}, rinv1[4] = {0.f, 0.f, 0.f, 0.f};

  for (int pass = 0; pass < 2; pass++){
    // prologue: stage step 0 -> buf 0
    #pragma unroll
    for (int i = 0; i < 10; i++)
      gload_lds16(Bf + ((size_t)i * 256 + tid) * 8, (void*)&sB[0][(i * 256 + tid) * 8]);

    for (int s = 0; s < NSTEPS; s++){
      const int buf = s & 1;
      if (s + 1 < NSTEPS){
        const unsigned short* src = Bf + (size_t)(s + 1) * CHUNKS_STEP * 8;
        #pragma unroll
        for (int i = 0; i < 10; i++)
          gload_lds16(src + ((size_t)i * 256 + tid) * 8, (void*)&sB[buf ^ 1][(i * 256 + tid) * 8]);
        asm volatile("s_waitcnt vmcnt(10)" ::: "memory");
      } else {
        asm volatile("s_waitcnt vmcnt(0)" ::: "memory");
      }
      __builtin_amdgcn_s_barrier();
      __builtin_amdgcn_sched_barrier(0);

      f32x4 acc0[5], acc1[5];
      #pragma unroll
      for (int ct = 0; ct < 5; ct++){
        acc0[ct] = (f32x4){0.f, 0.f, 0.f, 0.f};
        acc1[ct] = (f32x4){0.f, 0.f, 0.f, 0.f};
      }
      #pragma unroll
      for (int kt = 0; kt < 8; kt++){
        short8 b[5];
        #pragma unroll
        for (int ct = 0; ct < 5; ct++)
          b[ct] = *reinterpret_cast<const short8*>(&sB[buf][((ct * 8 + kt) * 64 + lane) * 8]);
        #pragma unroll
        for (int ct = 0; ct < 5; ct++){
          acc0[ct] = __builtin_amdgcn_mfma_f32_16x16x32_bf16(a0[kt], b[ct], acc0[ct], 0, 0, 0);
          if (has2)
            acc1[ct] = __builtin_amdgcn_mfma_f32_16x16x32_bf16(a1[kt], b[ct], acc1[ct], 0, 0, 0);
        }
      }
      __builtin_amdgcn_sched_barrier(0);
      __builtin_amdgcn_s_barrier();

      const int c0 = s * (CT_STEP * 16);
      #pragma unroll
      for (int ct = 0; ct < 5; ct++){
        const int gcol = c0 + ct * 16 + fr;
        const float obv = ob[gcol];
        #pragma unroll
        for (int r = 0; r < 4; r++){
          if (pass == 0){
            rs0[r] += __expf(acc0[ct][r] + obv);
            if (has2) rs1[r] += __expf(acc1[ct][r] + obv);
          } else {
            const int grow0 = R0 * 16 + fq * 4 + r;
            out[(size_t)grow0 * NP + gcol] = rinv0[r] * __expf(acc0[ct][r] + obv);
            if (has2){
              const int grow1 = R1 * 16 + fq * 4 + r;
              out[(size_t)grow1 * NP + gcol] = rinv1[r] * __expf(acc1[ct][r] + obv);
            }
          }
        }
      }
    }
    if (pass == 0){
      #pragma unroll
      for (int r = 0; r < 4; r++){
        float v0 = rs0[r], v1 = rs1[r];
        #pragma unroll
        for (int off = 1; off < 16; off <<= 1){
          v0 += __shfl_xor(v0, off, 64);
          v1 += __shfl_xor(v1, off, 64);
        }
        rinv0[r] = 1.f / v0;
        rinv1[r] = 1.f / v1;
      }
    }
  }
}

// ---------------- host ----------------
extern "C" void kernel_launch(void* const* d_in, const int* in_sizes, int n_in,
                              void* d_out, int out_size, void* d_ws, size_t ws_size,
                              hipStream_t stream){
  const int*   user_ids = (const int*)d_in[0];
  const int*   prod_ids = (const int*)d_in[1];
  const int*   ei_u     = (const int*)d_in[2];
  const int*   ei_p     = (const int*)d_in[3];
  const float* utab     = (const float*)d_in[4];
  const float* ptab     = (const float*)d_in[5];
  const float* uW       = (const float*)d_in[6];
  const float* ub       = (const float*)d_in[7];
  const float* pW       = (const float*)d_in[8];
  const float* pb       = (const float*)d_in[9];
  const float* oW       = (const float*)d_in[10];
  const float* ob       = (const float*)d_in[11];
  float* out = (float*)d_out;
  (void)in_sizes; (void)n_in; (void)out_size; (void)ws_size;

  char* w = (char*)d_ws;
  size_t off = 0;
  auto alloc = [&](size_t bytes)->void*{
    void* p = w + off; off += (bytes + 255) & ~(size_t)255; return p;
  };
  int*   cnt_u  = (int*)alloc(NN * 4);
  int*   cnt_p  = (int*)alloc(NN * 4);
  float* dinv_u = (float*)alloc(NN * 4);
  float* dinv_p = (float*)alloc(NN * 4);
  int*   ro_u   = (int*)alloc((NN + 1) * 4);
  int*   ro_p   = (int*)alloc((NN + 1) * 4);
  int*   cur_u  = (int*)alloc(NN * 4);
  int*   cur_p  = (int*)alloc(NN * 4);
  int*   col_u  = (int*)alloc((size_t)NE * 4);
  int*   col_p  = (int*)alloc((size_t)NE * 4);
  unsigned short* xu_f  = (unsigned short*)alloc((size_t)NN * DD * 2);
  unsigned short* xp_f  = (unsigned short*)alloc((size_t)NN * DD * 2);
  unsigned short* xu2_f = (unsigned short*)alloc((size_t)NN * DD * 2);
  unsigned short* xp2_f = (unsigned short*)alloc((size_t)NN * DD * 2);
  unsigned short* comb_f= (unsigned short*)alloc((size_t)NN * KO * 2);
  float* hs   = (float*)alloc((size_t)NN * DD * 4);
  unsigned short* WuF0 = (unsigned short*)alloc((size_t)DD * DD * 2);
  unsigned short* WuF1 = (unsigned short*)alloc((size_t)DD * DD * 2);
  unsigned short* WpF0 = (unsigned short*)alloc((size_t)DD * DD * 2);
  unsigned short* WpF1 = (unsigned short*)alloc((size_t)DD * DD * 2);
  unsigned short* WoF  = (unsigned short*)alloc((size_t)NP * KO * 2);

  hipMemsetAsync(cnt_u, 0, NN * 4, stream);
  hipMemsetAsync(cnt_p, 0, NN * 4, stream);

  const int* src_u = ei_u;  const int* dst_u = ei_u + NE;
  const int* src_p = ei_p;  const int* dst_p = ei_p + NE;

  k_count<<<(NE + 255) / 256, 256, 0, stream>>>(dst_u, cnt_u, NE);
  k_count<<<(NE + 255) / 256, 256, 0, stream>>>(dst_p, cnt_p, NE);
  k_dinv<<<(NN + 255) / 256, 256, 0, stream>>>(cnt_u, dinv_u, NN);
  k_dinv<<<(NN + 255) / 256, 256, 0, stream>>>(cnt_p, dinv_p, NN);
  k_scan<<<1, 1024, 0, stream>>>(cnt_u, ro_u, cur_u, NN);
  k_scan<<<1, 1024, 0, stream>>>(cnt_p, ro_p, cur_p, NN);
  k_fill<<<(NE + 255) / 256, 256, 0, stream>>>(src_u, dst_u, cur_u, col_u, NE);
  k_fill<<<(NE + 255) / 256, 256, 0, stream>>>(src_p, dst_p, cur_p, col_p, NE);

  dim3 gblk(32, 8);
  k_gather_frag<<<NN / 8, gblk, 0, stream>>>(utab, user_ids, xu_f);
  k_gather_frag<<<NN / 8, gblk, 0, stream>>>(ptab, prod_ids, xp_f);

  const int wtotS = DD * DD;
  k_wfrag<<<(wtotS + 255) / 256, 256, 0, stream>>>(uW,                    WuF0, DD, 2, wtotS);
  k_wfrag<<<(wtotS + 255) / 256, 256, 0, stream>>>(uW + (size_t)DD * DD,  WuF1, DD, 2, wtotS);
  k_wfrag<<<(wtotS + 255) / 256, 256, 0, stream>>>(pW,                    WpF0, DD, 2, wtotS);
  k_wfrag<<<(wtotS + 255) / 256, 256, 0, stream>>>(pW + (size_t)DD * DD,  WpF1, DD, 2, wtotS);
  const int wtotO = KO * NP;
  k_wfrag<<<(wtotO + 255) / 256, 256, 0, stream>>>(oW, WoF, NP, 3, wtotO);

  const int convGrid = (NN / 16 + 3) / 4;   // 313

  // layer 1
  k_conv<<<convGrid, 256, 0, stream>>>(xu_f, WuF0, dinv_u, hs);
  k_agg_frag<<<NN / 8, gblk, 0, stream>>>(hs, dinv_u, ro_u, col_u, ub, xu2_f, 4, 0);
  k_conv<<<convGrid, 256, 0, stream>>>(xp_f, WpF0, dinv_p, hs);
  k_agg_frag<<<NN / 8, gblk, 0, stream>>>(hs, dinv_p, ro_p, col_p, pb, xp2_f, 4, 0);

  // layer 2 -> comb fragments (user ktiles 0..3, product ktiles 4..7)
  k_conv<<<convGrid, 256, 0, stream>>>(xu2_f, WuF1, dinv_u, hs);
  k_agg_frag<<<NN / 8, gblk, 0, stream>>>(hs, dinv_u, ro_u, col_u, ub + DD, comb_f, 8, 0);
  k_conv<<<convGrid, 256, 0, stream>>>(xp2_f, WpF1, dinv_p, hs);
  k_agg_frag<<<NN / 8, gblk, 0, stream>>>(hs, dinv_p, ro_p, col_p, pb + DD, comb_f, 8, 4);

  // fused output GEMM + softmax
  k_out<<<250, 256, 0, stream>>>(comb_f, WoF, ob, out);
}

// Round 3
// 1282.977 us; speedup vs baseline: 2.2311x; 2.2311x over previous
//
#include <hip/hip_runtime.h>
#include <cstdint>
#include <cstddef>

#define NN 20000      // nodes
#define NE 640000     // edges
#define DD 128        // feature dim
#define NP 10000      // products (output cols)
#define KO 256        // 2*DD
#define NRT 1250      // NN/16 row-tiles
#define NRT_PAD 1256  // padded to 157*8
#define NCT_PAD 632   // padded col-tiles: 79*8

typedef __attribute__((ext_vector_type(8))) short short8;
typedef __attribute__((ext_vector_type(4))) float f32x4;

static __device__ __forceinline__ unsigned short f2bf(float f){
  uint32_t u = __float_as_uint(f);
  return (unsigned short)((u + 0x7fffu + ((u >> 16) & 1u)) >> 16);
}
static __device__ __forceinline__ float bf2f(unsigned short u){
  return __uint_as_float(((uint32_t)u) << 16);
}

static __device__ __forceinline__ void gload_lds16(const void* g, void* l){
  __builtin_amdgcn_global_load_lds(
      (const __attribute__((address_space(1))) void*)g,
      (__attribute__((address_space(3))) void*)l, 16, 0, 0);
}

// ---------------- CSR build ----------------
__global__ void k_count(const int* __restrict__ dst, int* __restrict__ cnt, int n){
  int i = blockIdx.x * blockDim.x + threadIdx.x;
  if (i < n) atomicAdd(&cnt[dst[i]], 1);
}

__global__ void k_dinv(const int* __restrict__ cnt, float* __restrict__ dinv, int n){
  int i = blockIdx.x * blockDim.x + threadIdx.x;
  if (i < n) dinv[i] = rsqrtf((float)(cnt[i] + 1));  // +1 self-loop
}

__global__ void k_scan(const int* __restrict__ cnt, int* __restrict__ row_off,
                       int* __restrict__ cursor, int n){
  __shared__ int part[1024];
  int t = threadIdx.x;
  int per = (n + 1023) >> 10;
  int base = t * per;
  int s = 0;
  for (int i = 0; i < per; i++){ int idx = base + i; if (idx < n) s += cnt[idx]; }
  part[t] = s;
  __syncthreads();
  for (int off = 1; off < 1024; off <<= 1){
    int v = (t >= off) ? part[t - off] : 0;
    __syncthreads();
    part[t] += v;
    __syncthreads();
  }
  int run = (t == 0) ? 0 : part[t - 1];
  for (int i = 0; i < per; i++){
    int idx = base + i;
    if (idx < n){ row_off[idx] = run; cursor[idx] = run; run += cnt[idx]; }
  }
  if (t == 0) row_off[n] = part[1023];
}

__global__ void k_fill(const int* __restrict__ src, const int* __restrict__ dst,
                       int* __restrict__ cursor, int* __restrict__ col, int n){
  int i = blockIdx.x * blockDim.x + threadIdx.x;
  if (i < n){
    int p = atomicAdd(&cursor[dst[i]], 1);
    col[p] = src[i];
  }
}

// ---------------- packers (MFMA fragment order) ----------------
// frag layout: chunk[(rowtile*KT + ktile)*64 + k8*16 + fr][e]
//   holds X[rowtile*16 + fr][ktile*32 + k8*8 + e], chunk = 8 bf16 = 16B

__global__ void k_gather_frag(const float* __restrict__ tab, const int* __restrict__ ids,
                              unsigned short* __restrict__ xf){
  int node = blockIdx.x * blockDim.y + threadIdx.y;
  int tx = threadIdx.x;            // covers d = tx*4 .. tx*4+3
  if (node >= NN) return;
  const float4 v = *reinterpret_cast<const float4*>(tab + (size_t)ids[node] * DD + tx * 4);
  ushort4 o; o.x = f2bf(v.x); o.y = f2bf(v.y); o.z = f2bf(v.z); o.w = f2bf(v.w);
  size_t chunk = ((size_t)(node >> 4) * 4 + (tx >> 3)) * 64 + ((tx >> 1) & 3) * 16 + (node & 15);
  *reinterpret_cast<ushort4*>(xf + chunk * 8 + (tx & 1) * 4) = o;
}

// W [K][ncols] row-major f32 -> B-fragment order bf16, col-padded with zeros
__global__ void k_wfrag(const float* __restrict__ W, unsigned short* __restrict__ Wf,
                        int ncols, int lg2kt, int total){
  int i = blockIdx.x * blockDim.x + threadIdx.x;
  if (i >= total) return;
  int e = i & 7, l = (i >> 3) & 63, rem = i >> 9;
  int kt = rem & ((1 << lg2kt) - 1), ct = rem >> lg2kt;
  int col = ct * 16 + (l & 15);
  int k = kt * 32 + (l >> 4) * 8 + e;
  Wf[i] = (col < ncols) ? f2bf(W[(size_t)k * ncols + col]) : (unsigned short)0;
}

// ---------------- conv GEMM: hs = dinv * (x @ W), A in regs, no LDS ----------------
__global__ __launch_bounds__(256) void k_conv(const unsigned short* __restrict__ Af,
        const unsigned short* __restrict__ Wf, const float* __restrict__ dinv,
        float* __restrict__ hs){
  int gw = blockIdx.x * 4 + (threadIdx.x >> 6);
  int lane = threadIdx.x & 63;
  bool valid = gw < NRT;
  int R = valid ? gw : (NRT - 1);
  short8 a[4];
  #pragma unroll
  for (int kt = 0; kt < 4; kt++)
    a[kt] = *reinterpret_cast<const short8*>(Af + ((size_t)(R * 4 + kt) * 64 + lane) * 8);
  int fr = lane & 15, fq = lane >> 4;
  #pragma unroll
  for (int ct = 0; ct < 8; ct++){
    f32x4 acc = {0.f, 0.f, 0.f, 0.f};
    #pragma unroll
    for (int kt = 0; kt < 4; kt++){
      short8 b = *reinterpret_cast<const short8*>(Wf + ((size_t)(ct * 4 + kt) * 64 + lane) * 8);
      acc = __builtin_amdgcn_mfma_f32_16x16x32_bf16(a[kt], b, acc, 0, 0, 0);
    }
    if (valid){
      #pragma unroll
      for (int r = 0; r < 4; r++){
        int grow = R * 16 + fq * 4 + r;
        hs[(size_t)grow * DD + ct * 16 + fr] = dinv[grow] * acc[r];
      }
    }
  }
}

// ---------------- aggregation -> frag bf16 ----------------
__global__ void k_agg_frag(const float* __restrict__ hs, const float* __restrict__ dinv,
                           const int* __restrict__ row_off, const int* __restrict__ col,
                           const float* __restrict__ bias, unsigned short* __restrict__ xf,
                           int KT, int toff){
  int node = blockIdx.x * blockDim.y + threadIdx.y;
  int tx = threadIdx.x;
  if (node >= NN) return;
  const float4* h4 = reinterpret_cast<const float4*>(hs);
  float4 acc = h4[(size_t)node * 32 + tx];   // self term (hs pre-scaled by dinv)
  int s = row_off[node], e = row_off[node + 1];
  int i = s;
  for (; i + 1 < e; i += 2){
    int c0 = col[i], c1 = col[i + 1];
    float4 v0 = h4[(size_t)c0 * 32 + tx];
    float4 v1 = h4[(size_t)c1 * 32 + tx];
    acc.x += v0.x + v1.x; acc.y += v0.y + v1.y;
    acc.z += v0.z + v1.z; acc.w += v0.w + v1.w;
  }
  if (i < e){
    float4 v = h4[(size_t)col[i] * 32 + tx];
    acc.x += v.x; acc.y += v.y; acc.z += v.z; acc.w += v.w;
  }
  float dn = dinv[node];
  const float4 b4 = *reinterpret_cast<const float4*>(bias + tx * 4);
  ushort4 o;
  o.x = f2bf(dn * acc.x + b4.x); o.y = f2bf(dn * acc.y + b4.y);
  o.z = f2bf(dn * acc.z + b4.z); o.w = f2bf(dn * acc.w + b4.w);
  size_t chunk = ((size_t)(node >> 4) * KT + toff + (tx >> 3)) * 64 + ((tx >> 1) & 3) * 16 + (node & 15);
  *reinterpret_cast<ushort4*>(xf + chunk * 8 + (tx & 1) * 4) = o;
}

// ---------------- big GEMM (M=20096pad, N=10112pad, K=256) + exp + rowsum ----------------
// grid (157, 79), 256 thr, 4 waves as 2x2 of 64x64; BK=64 single-buffered.
// STORE_BF16=1: store bf16 logits to wsb. STORE_BF16=0: store exp(z) fp32 to out.
template<int STORE_BF16>
__global__ __launch_bounds__(256) void k_big(const unsigned short* __restrict__ Af,
        const unsigned short* __restrict__ Bf, const float* __restrict__ ob,
        float* __restrict__ rowsum, unsigned short* __restrict__ wsb,
        float* __restrict__ out){
  __shared__ unsigned short sA[1024 * 8];   // 16KB: [rt8][kt2][lane64][e8]
  __shared__ unsigned short sB[1024 * 8];
  const int tid = threadIdx.x, lane = tid & 63, wid = tid >> 6;
  const int wm = wid >> 1, wn = wid & 1;
  const int brt = blockIdx.x * 8;   // base 16-row tile
  const int bct = blockIdx.y * 8;   // base 16-col tile

  f32x4 acc[4][4] = {};

  for (int s = 0; s < 4; s++){
    #pragma unroll
    for (int i = 0; i < 4; i++){
      int c = i * 256 + tid;
      int rt = c >> 7, kt = (c >> 6) & 1, ln = c & 63;
      gload_lds16(Af + (((size_t)(brt + rt) * 8 + s * 2 + kt) * 64 + ln) * 8,
                  (void*)&sA[(size_t)c * 8]);
      gload_lds16(Bf + (((size_t)(bct + rt) * 8 + s * 2 + kt) * 64 + ln) * 8,
                  (void*)&sB[(size_t)c * 8]);
    }
    __syncthreads();
    #pragma unroll
    for (int kk = 0; kk < 2; kk++){
      short8 av[4], bv[4];
      #pragma unroll
      for (int m = 0; m < 4; m++)
        av[m] = *reinterpret_cast<const short8*>(&sA[(((wm * 4 + m) * 2 + kk) * 64 + lane) * 8]);
      #pragma unroll
      for (int n = 0; n < 4; n++)
        bv[n] = *reinterpret_cast<const short8*>(&sB[(((wn * 4 + n) * 2 + kk) * 64 + lane) * 8]);
      #pragma unroll
      for (int m = 0; m < 4; m++)
        #pragma unroll
        for (int n = 0; n < 4; n++)
          acc[m][n] = __builtin_amdgcn_mfma_f32_16x16x32_bf16(av[m], bv[n], acc[m][n], 0, 0, 0);
    }
    __syncthreads();
  }

  const int fr = lane & 15, fq = lane >> 4;
  const int row0 = brt * 16 + wm * 64, col0 = bct * 16 + wn * 64;
  #pragma unroll
  for (int m = 0; m < 4; m++){
    #pragma unroll
    for (int r = 0; r < 4; r++){
      const int grow = row0 + m * 16 + fq * 4 + r;
      const bool rv = grow < NN;
      float rsum = 0.f;
      #pragma unroll
      for (int n = 0; n < 4; n++){
        const int gcol = col0 + n * 16 + fr;
        const bool cv = gcol < NP;
        const float obv = cv ? ob[gcol] : 0.f;
        const float z = acc[m][n][r] + obv;
        const float e = cv ? __expf(z) : 0.f;
        rsum += e;
        if (rv && cv){
          if (STORE_BF16) wsb[(size_t)grow * NP + gcol] = f2bf(z);
          else            out[(size_t)grow * NP + gcol] = e;
        }
      }
      rsum += __shfl_xor(rsum, 1, 64);
      rsum += __shfl_xor(rsum, 2, 64);
      rsum += __shfl_xor(rsum, 4, 64);
      rsum += __shfl_xor(rsum, 8, 64);
      if (fr == 0 && rv) atomicAdd(&rowsum[grow], rsum);
    }
  }
}

// path A: out = exp(bf16 logit) / rowsum
__global__ __launch_bounds__(256) void k_rescale(const unsigned short* __restrict__ wsb,
        const float* __restrict__ rowsum, float* __restrict__ out){
  const int row = blockIdx.x;
  const float rinv = 1.f / rowsum[row];
  const short8* src = reinterpret_cast<const short8*>(wsb + (size_t)row * NP);
  float* orow = out + (size_t)row * NP;
  for (int c8 = threadIdx.x; c8 < NP / 8; c8 += 256){
    short8 v = src[c8];
    float4 o0, o1;
    o0.x = __expf(bf2f((unsigned short)v[0])) * rinv;
    o0.y = __expf(bf2f((unsigned short)v[1])) * rinv;
    o0.z = __expf(bf2f((unsigned short)v[2])) * rinv;
    o0.w = __expf(bf2f((unsigned short)v[3])) * rinv;
    o1.x = __expf(bf2f((unsigned short)v[4])) * rinv;
    o1.y = __expf(bf2f((unsigned short)v[5])) * rinv;
    o1.z = __expf(bf2f((unsigned short)v[6])) * rinv;
    o1.w = __expf(bf2f((unsigned short)v[7])) * rinv;
    *reinterpret_cast<float4*>(orow + c8 * 8)     = o0;
    *reinterpret_cast<float4*>(orow + c8 * 8 + 4) = o1;
  }
}

// path B: in-place scale
__global__ void k_scale(float* __restrict__ out, const float* __restrict__ rowsum){
  int row = blockIdx.y;
  int c4 = blockIdx.x * blockDim.x + threadIdx.x;
  if (c4 >= NP / 4) return;
  float r = 1.f / rowsum[row];
  float4* p = reinterpret_cast<float4*>(out + (size_t)row * NP) + c4;
  float4 v = *p;
  v.x *= r; v.y *= r; v.z *= r; v.w *= r;
  *p = v;
}

// ---------------- host ----------------
extern "C" void kernel_launch(void* const* d_in, const int* in_sizes, int n_in,
                              void* d_out, int out_size, void* d_ws, size_t ws_size,
                              hipStream_t stream){
  const int*   user_ids = (const int*)d_in[0];
  const int*   prod_ids = (const int*)d_in[1];
  const int*   ei_u     = (const int*)d_in[2];
  const int*   ei_p     = (const int*)d_in[3];
  const float* utab     = (const float*)d_in[4];
  const float* ptab     = (const float*)d_in[5];
  const float* uW       = (const float*)d_in[6];
  const float* ub       = (const float*)d_in[7];
  const float* pW       = (const float*)d_in[8];
  const float* pb       = (const float*)d_in[9];
  const float* oW       = (const float*)d_in[10];
  const float* ob       = (const float*)d_in[11];
  float* out = (float*)d_out;
  (void)in_sizes; (void)n_in; (void)out_size;

  char* w = (char*)d_ws;
  size_t off = 0;
  auto alloc = [&](size_t bytes)->void*{
    void* p = w + off; off += (bytes + 255) & ~(size_t)255; return p;
  };
  int*   cnt_u  = (int*)alloc(NN * 4);
  int*   cnt_p  = (int*)alloc(NN * 4);
  float* dinv_u = (float*)alloc(NN * 4);
  float* dinv_p = (float*)alloc(NN * 4);
  int*   ro_u   = (int*)alloc((NN + 1) * 4);
  int*   ro_p   = (int*)alloc((NN + 1) * 4);
  int*   cur_u  = (int*)alloc(NN * 4);
  int*   cur_p  = (int*)alloc(NN * 4);
  int*   col_u  = (int*)alloc((size_t)NE * 4);
  int*   col_p  = (int*)alloc((size_t)NE * 4);
  unsigned short* xu_f  = (unsigned short*)alloc((size_t)NN * DD * 2);
  unsigned short* xp_f  = (unsigned short*)alloc((size_t)NN * DD * 2);
  unsigned short* xu2_f = (unsigned short*)alloc((size_t)NN * DD * 2);
  unsigned short* xp2_f = (unsigned short*)alloc((size_t)NN * DD * 2);
  unsigned short* comb_f= (unsigned short*)alloc((size_t)NRT_PAD * 8 * 64 * 8 * 2);
  float* hs   = (float*)alloc((size_t)NN * DD * 4);
  unsigned short* WuF0 = (unsigned short*)alloc((size_t)DD * DD * 2);
  unsigned short* WuF1 = (unsigned short*)alloc((size_t)DD * DD * 2);
  unsigned short* WpF0 = (unsigned short*)alloc((size_t)DD * DD * 2);
  unsigned short* WpF1 = (unsigned short*)alloc((size_t)DD * DD * 2);
  unsigned short* WoF  = (unsigned short*)alloc((size_t)NCT_PAD * 8 * 64 * 8 * 2);
  float* rowsum = (float*)alloc(NN * 4);

  const size_t need_ws = (size_t)NN * NP * 2;  // 400 MB bf16 logits
  unsigned short* wsb = nullptr;
  bool pathA = (ws_size > off) && (ws_size - off >= need_ws);
  if (pathA) wsb = (unsigned short*)alloc(need_ws);

  hipMemsetAsync(cnt_u, 0, NN * 4, stream);
  hipMemsetAsync(cnt_p, 0, NN * 4, stream);
  hipMemsetAsync(rowsum, 0, NN * 4, stream);
  hipMemsetAsync(comb_f, 0, (size_t)NRT_PAD * 8 * 64 * 8 * 2, stream);  // zero pad rowtiles

  const int* src_u = ei_u;  const int* dst_u = ei_u + NE;
  const int* src_p = ei_p;  const int* dst_p = ei_p + NE;

  k_count<<<(NE + 255) / 256, 256, 0, stream>>>(dst_u, cnt_u, NE);
  k_count<<<(NE + 255) / 256, 256, 0, stream>>>(dst_p, cnt_p, NE);
  k_dinv<<<(NN + 255) / 256, 256, 0, stream>>>(cnt_u, dinv_u, NN);
  k_dinv<<<(NN + 255) / 256, 256, 0, stream>>>(cnt_p, dinv_p, NN);
  k_scan<<<1, 1024, 0, stream>>>(cnt_u, ro_u, cur_u, NN);
  k_scan<<<1, 1024, 0, stream>>>(cnt_p, ro_p, cur_p, NN);
  k_fill<<<(NE + 255) / 256, 256, 0, stream>>>(src_u, dst_u, cur_u, col_u, NE);
  k_fill<<<(NE + 255) / 256, 256, 0, stream>>>(src_p, dst_p, cur_p, col_p, NE);

  dim3 gblk(32, 8);
  k_gather_frag<<<NN / 8, gblk, 0, stream>>>(utab, user_ids, xu_f);
  k_gather_frag<<<NN / 8, gblk, 0, stream>>>(ptab, prod_ids, xp_f);

  const int wtotS = DD * DD;
  k_wfrag<<<(wtotS + 255) / 256, 256, 0, stream>>>(uW,                    WuF0, DD, 2, wtotS);
  k_wfrag<<<(wtotS + 255) / 256, 256, 0, stream>>>(uW + (size_t)DD * DD,  WuF1, DD, 2, wtotS);
  k_wfrag<<<(wtotS + 255) / 256, 256, 0, stream>>>(pW,                    WpF0, DD, 2, wtotS);
  k_wfrag<<<(wtotS + 255) / 256, 256, 0, stream>>>(pW + (size_t)DD * DD,  WpF1, DD, 2, wtotS);
  const int wtotO = NCT_PAD * 8 * 64 * 8;
  k_wfrag<<<(wtotO + 255) / 256, 256, 0, stream>>>(oW, WoF, NP, 3, wtotO);

  const int convGrid = (NRT + 3) / 4;   // 313

  // layer 1
  k_conv<<<convGrid, 256, 0, stream>>>(xu_f, WuF0, dinv_u, hs);
  k_agg_frag<<<NN / 8, gblk, 0, stream>>>(hs, dinv_u, ro_u, col_u, ub, xu2_f, 4, 0);
  k_conv<<<convGrid, 256, 0, stream>>>(xp_f, WpF0, dinv_p, hs);
  k_agg_frag<<<NN / 8, gblk, 0, stream>>>(hs, dinv_p, ro_p, col_p, pb, xp2_f, 4, 0);

  // layer 2 -> comb fragments (user ktiles 0..3, product ktiles 4..7)
  k_conv<<<convGrid, 256, 0, stream>>>(xu2_f, WuF1, dinv_u, hs);
  k_agg_frag<<<NN / 8, gblk, 0, stream>>>(hs, dinv_u, ro_u, col_u, ub + DD, comb_f, 8, 0);
  k_conv<<<convGrid, 256, 0, stream>>>(xp2_f, WpF1, dinv_p, hs);
  k_agg_frag<<<NN / 8, gblk, 0, stream>>>(hs, dinv_p, ro_p, col_p, pb + DD, comb_f, 8, 4);

  // big GEMM + exp + rowsum, then normalize
  dim3 bigGrid(157, 79);
  if (pathA){
    k_big<1><<<bigGrid, 256, 0, stream>>>(comb_f, WoF, ob, rowsum, wsb, out);
    k_rescale<<<NN, 256, 0, stream>>>(wsb, rowsum, out);
  } else {
    k_big<0><<<bigGrid, 256, 0, stream>>>(comb_f, WoF, ob, rowsum, nullptr, out);
    k_scale<<<dim3((NP / 4 + 255) / 256, NN), 256, 0, stream>>>(out, rowsum);
  }
}